// Round 1
// baseline (673.625 us; speedup 1.0000x reference)
//
#include <hip/hip_runtime.h>
#include <hip/hip_bf16.h>
#include <cstdint>
#include <cstddef>

// Problem constants
#define NB   64
#define NS   8
#define DIM  2048
#define FF   4096
#define NE   8
#define TOK  512            // NB*NS
#define NPAIR 1024          // TOK*2

typedef __attribute__((ext_vector_type(4))) float f32x4;
typedef __attribute__((ext_vector_type(8))) short bf16x8;

#define MFMA16(a, b, c) __builtin_amdgcn_mfma_f32_16x16x32_bf16((a), (b), (c), 0, 0, 0)

static __device__ __forceinline__ short f2bf(float f) {
    unsigned u = __builtin_bit_cast(unsigned, f);
    unsigned r = (u + 0x7fffu + ((u >> 16) & 1u)) >> 16;
    return (short)r;
}

// ---------------------------------------------------------------------------
// Kernel 1: gating — per-token logits (x . gate_w), top-2, softmax over k.
// One 64-thread wave per token.
// ---------------------------------------------------------------------------
__global__ void gate_topk(const float* __restrict__ x, const float* __restrict__ gw,
                          int* __restrict__ tok_expert, float* __restrict__ tok_gatew) {
    int token = blockIdx.x;
    int lane  = threadIdx.x;
    const float* xr = x + (size_t)token * DIM;

    float acc[NE];
#pragma unroll
    for (int e = 0; e < NE; ++e) acc[e] = 0.f;

    for (int d0 = lane * 8; d0 < DIM; d0 += 64 * 8) {
        float4 xa = *(const float4*)(xr + d0);
        float4 xb = *(const float4*)(xr + d0 + 4);
#pragma unroll
        for (int j = 0; j < 8; ++j) {
            float xv = (j < 4) ? ((const float*)&xa)[j] : ((const float*)&xb)[j - 4];
            const float4* g = (const float4*)(gw + (size_t)(d0 + j) * NE);
            float4 g0 = g[0], g1 = g[1];
            acc[0] += xv * g0.x; acc[1] += xv * g0.y;
            acc[2] += xv * g0.z; acc[3] += xv * g0.w;
            acc[4] += xv * g1.x; acc[5] += xv * g1.y;
            acc[6] += xv * g1.z; acc[7] += xv * g1.w;
        }
    }
#pragma unroll
    for (int off = 32; off >= 1; off >>= 1) {
#pragma unroll
        for (int e = 0; e < NE; ++e) acc[e] += __shfl_down(acc[e], off);
    }
    if (lane == 0) {
        float b1 = -1e30f, b2 = -1e30f; int i1 = 0, i2 = 0;
#pragma unroll
        for (int e = 0; e < NE; ++e) {
            float v = acc[e];
            if (v > b1) { b2 = b1; i2 = i1; b1 = v; i1 = e; }
            else if (v > b2) { b2 = v; i2 = e; }
        }
        float t = __expf(b2 - b1);
        float w0 = 1.f / (1.f + t);
        float w1v = t / (1.f + t);
        tok_expert[token * 2 + 0] = i1;
        tok_expert[token * 2 + 1] = i2;
        tok_gatew[token * 2 + 0] = w0;
        tok_gatew[token * 2 + 1] = w1v;
    }
}

// ---------------------------------------------------------------------------
// Kernel 2: build deterministic per-expert token lists.
// 1 block, 512 threads = 8 waves; wave w handles expert w with ballot scan.
// ---------------------------------------------------------------------------
__global__ void build_lists(const int* __restrict__ tok_expert,
                            const float* __restrict__ tok_gatew,
                            int* __restrict__ counts, int* __restrict__ offsets,
                            int* __restrict__ row_token, float* __restrict__ row_gatew,
                            int* __restrict__ pair_row) {
    __shared__ int s_off[NE];
    int e    = threadIdx.x >> 6;
    int lane = threadIdx.x & 63;
    unsigned long long lt = (1ull << lane) - 1ull;

    // pass 1: counts
    int cnt = 0;
    __shared__ int s_cnt[NE];
    for (int base = 0; base < NPAIR; base += 64) {
        int id = tok_expert[base + lane];
        unsigned long long m = __ballot(id == e);
        cnt += __popcll(m);
    }
    if (lane == 0) s_cnt[e] = cnt;
    __syncthreads();
    if (threadIdx.x == 0) {
        int o = 0;
        for (int i = 0; i < NE; ++i) {
            int c = s_cnt[i];
            counts[i] = c;
            offsets[i] = o;
            s_off[i] = o;
            o += c;
        }
    }
    __syncthreads();

    // pass 2: write rows in deterministic (entry-order) sequence
    int rbase = s_off[e];
    for (int base = 0; base < NPAIR; base += 64) {
        int entry = base + lane;
        int id = tok_expert[entry];
        bool match = (id == e);
        unsigned long long m = __ballot(match);
        int pre = __popcll(m & lt);
        if (match) {
            int row = rbase + pre;
            row_token[row] = entry >> 1;
            row_gatew[row] = tok_gatew[entry];
            pair_row[entry] = row;
        }
        rbase += __popcll(m);
    }
}

// ---------------------------------------------------------------------------
// Kernel 3: H = silu(X*w1) .* (X*w3) for each expert's token group.
// grid = NE * 64 (expert x f-tile of 64 cols). 256 thr = 4 waves.
// wave owns 48 rows x 64 cols; M capacity 192/block-pass; K-loop over D.
// Weights are read exactly once from HBM (each block owns its f-tile).
// ---------------------------------------------------------------------------
__global__ __launch_bounds__(256, 2) void ffn1(
    const float* __restrict__ x, const float* __restrict__ w1,
    const float* __restrict__ w3,
    const int* __restrict__ counts, const int* __restrict__ offsets,
    const int* __restrict__ row_token, unsigned short* __restrict__ Hbuf) {
    int e  = blockIdx.x >> 6;
    int f0 = (blockIdx.x & 63) * 64;
    int w    = threadIdx.x >> 6;
    int lane = threadIdx.x & 63;
    int l15 = lane & 15, lg = lane >> 4;

    int Me = counts[e];
    if (Me == 0) return;
    int off = offsets[e];

    const float* w1e = w1 + (size_t)e * DIM * FF;
    const float* w3e = w3 + (size_t)e * DIM * FF;
    const float* col1 = w1e + f0 + l15;
    const float* col3 = w3e + f0 + l15;

    for (int sup = 0; sup * 192 < Me; ++sup) {
        int row0 = sup * 192 + w * 48;

        const float* xp[3];
#pragma unroll
        for (int m = 0; m < 3; ++m) {
            int rl = row0 + m * 16 + l15;
            int tok = (rl < Me) ? row_token[off + rl] : 0;
            xp[m] = x + (size_t)tok * DIM + lg * 8;
        }

        f32x4 acc1[3][4], acc3[3][4];
#pragma unroll
        for (int m = 0; m < 3; ++m)
#pragma unroll
            for (int cs = 0; cs < 4; ++cs) {
                acc1[m][cs] = (f32x4){0.f, 0.f, 0.f, 0.f};
                acc3[m][cs] = (f32x4){0.f, 0.f, 0.f, 0.f};
            }

        for (int kt = 0; kt < DIM / 32; ++kt) {
            int k0 = kt * 32;
            // A fragments: 8 contiguous k per lane, coalesced-ish 32B chunks
            bf16x8 af[3];
#pragma unroll
            for (int m = 0; m < 3; ++m) {
                float4 p = *(const float4*)(xp[m] + k0);
                float4 q = *(const float4*)(xp[m] + k0 + 4);
                af[m][0] = f2bf(p.x); af[m][1] = f2bf(p.y);
                af[m][2] = f2bf(p.z); af[m][3] = f2bf(p.w);
                af[m][4] = f2bf(q.x); af[m][5] = f2bf(q.y);
                af[m][6] = f2bf(q.z); af[m][7] = f2bf(q.w);
            }
            size_t krow = (size_t)(k0 + lg * 8) * FF;
#pragma unroll
            for (int cs = 0; cs < 4; ++cs) {
                const float* p1 = col1 + krow + cs * 16;
                const float* p3 = col3 + krow + cs * 16;
                float b1v[8], b3v[8];
#pragma unroll
                for (int j = 0; j < 8; ++j) {
                    b1v[j] = p1[(size_t)j * FF];
                    b3v[j] = p3[(size_t)j * FF];
                }
                bf16x8 bf1, bf3;
#pragma unroll
                for (int j = 0; j < 8; ++j) { bf1[j] = f2bf(b1v[j]); bf3[j] = f2bf(b3v[j]); }
#pragma unroll
                for (int m = 0; m < 3; ++m) {
                    acc1[m][cs] = MFMA16(af[m], bf1, acc1[m][cs]);
                    acc3[m][cs] = MFMA16(af[m], bf3, acc3[m][cs]);
                }
            }
        }

        // epilogue: silu(a1)*a3 -> bf16 H
#pragma unroll
        for (int m = 0; m < 3; ++m)
#pragma unroll
            for (int r = 0; r < 4; ++r) {
                int rl = row0 + m * 16 + lg * 4 + r;
                if (rl < Me) {
                    size_t hbase = (size_t)(off + rl) * FF + f0 + l15;
#pragma unroll
                    for (int cs = 0; cs < 4; ++cs) {
                        float a1 = acc1[m][cs][r];
                        float a3 = acc3[m][cs][r];
                        float h = (a1 / (1.f + __expf(-a1))) * a3;
                        Hbuf[hbase + cs * 16] = (unsigned short)f2bf(h);
                    }
                }
            }
    }
}

// ---------------------------------------------------------------------------
// Kernel 4: OutPair = (H @ w2) * gate_weight   (per pair row)
// grid = NE * 32 (expert x d-tile of 64 cols). Same structure; K over F.
// ---------------------------------------------------------------------------
__global__ __launch_bounds__(256, 2) void ffn2(
    const unsigned short* __restrict__ Hbuf, const float* __restrict__ w2,
    const int* __restrict__ counts, const int* __restrict__ offsets,
    const float* __restrict__ row_gatew, float* __restrict__ OP) {
    int e  = blockIdx.x >> 5;
    int d0 = (blockIdx.x & 31) * 64;
    int w    = threadIdx.x >> 6;
    int lane = threadIdx.x & 63;
    int l15 = lane & 15, lg = lane >> 4;

    int Me = counts[e];
    if (Me == 0) return;
    int off = offsets[e];

    const float* w2e = w2 + (size_t)e * FF * DIM;
    const float* colb = w2e + d0 + l15;

    for (int sup = 0; sup * 192 < Me; ++sup) {
        int row0 = sup * 192 + w * 48;

        const unsigned short* hp[3];
#pragma unroll
        for (int m = 0; m < 3; ++m) {
            int rl = row0 + m * 16 + l15;
            int ga = (rl < Me) ? (off + rl) : 0;
            hp[m] = Hbuf + (size_t)ga * FF + lg * 8;
        }

        f32x4 acc[3][4];
#pragma unroll
        for (int m = 0; m < 3; ++m)
#pragma unroll
            for (int cs = 0; cs < 4; ++cs) acc[m][cs] = (f32x4){0.f, 0.f, 0.f, 0.f};

        for (int kt = 0; kt < FF / 32; ++kt) {
            int k0 = kt * 32;
            bf16x8 af[3];
#pragma unroll
            for (int m = 0; m < 3; ++m)
                af[m] = *(const bf16x8*)(hp[m] + k0);   // 8 bf16, 16B aligned

            size_t krow = (size_t)(k0 + lg * 8) * DIM;
#pragma unroll
            for (int cs = 0; cs < 4; ++cs) {
                const float* p2 = colb + krow + cs * 16;
                float bv[8];
#pragma unroll
                for (int j = 0; j < 8; ++j) bv[j] = p2[(size_t)j * DIM];
                bf16x8 bfv;
#pragma unroll
                for (int j = 0; j < 8; ++j) bfv[j] = f2bf(bv[j]);
#pragma unroll
                for (int m = 0; m < 3; ++m)
                    acc[m][cs] = MFMA16(af[m], bfv, acc[m][cs]);
            }
        }

#pragma unroll
        for (int m = 0; m < 3; ++m)
#pragma unroll
            for (int r = 0; r < 4; ++r) {
                int rl = row0 + m * 16 + lg * 4 + r;
                if (rl < Me) {
                    int grow = off + rl;
                    float g = row_gatew[grow];
                    size_t obase = (size_t)grow * DIM + d0 + l15;
#pragma unroll
                    for (int cs = 0; cs < 4; ++cs)
                        OP[obase + cs * 16] = acc[m][cs][r] * g;
                }
            }
    }
}

// ---------------------------------------------------------------------------
// Kernel 5: out[token] = OP[pair0] + OP[pair1]   (gate weights already applied)
// ---------------------------------------------------------------------------
__global__ void combine(const float* __restrict__ OP, const int* __restrict__ pair_row,
                        float* __restrict__ out) {
    int idx = blockIdx.x * blockDim.x + threadIdx.x;   // 0 .. 262143 (float4 units)
    int token = idx >> 9;                              // 512 float4 per token
    int q = idx & 511;
    int r0 = pair_row[token * 2 + 0];
    int r1 = pair_row[token * 2 + 1];
    float4 a = *(const float4*)(OP + (size_t)r0 * DIM + q * 4);
    float4 b = *(const float4*)(OP + (size_t)r1 * DIM + q * 4);
    float4 o;
    o.x = a.x + b.x; o.y = a.y + b.y; o.z = a.z + b.z; o.w = a.w + b.w;
    *(float4*)(out + (size_t)token * DIM + q * 4) = o;
}

// ---------------------------------------------------------------------------
extern "C" void kernel_launch(void* const* d_in, const int* in_sizes, int n_in,
                              void* d_out, int out_size, void* d_ws, size_t ws_size,
                              hipStream_t stream) {
    const float* x  = (const float*)d_in[0];
    const float* gw = (const float*)d_in[1];
    const float* w1 = (const float*)d_in[2];
    const float* w3 = (const float*)d_in[3];
    const float* w2 = (const float*)d_in[4];
    float* out = (float*)d_out;

    char* ws = (char*)d_ws;
    // workspace layout
    unsigned short* Hbuf = (unsigned short*)ws;                   //  8 MB (bf16 [1024][4096])
    float* OP            = (float*)(ws + 8388608);                //  8 MB (f32  [1024][2048])
    char* meta           = ws + 16777216;
    int*   tok_expert = (int*)(meta);                             // [1024]
    float* tok_gatew  = (float*)(meta + 4096);                    // [1024]
    int*   counts     = (int*)(meta + 8192);                      // [8]
    int*   offsets    = (int*)(meta + 8224);                      // [8]
    int*   row_token  = (int*)(meta + 8256);                      // [1024]
    float* row_gatew  = (float*)(meta + 12352);                   // [1024]
    int*   pair_row   = (int*)(meta + 16448);                     // [1024]

    gate_topk<<<TOK, 64, 0, stream>>>(x, gw, tok_expert, tok_gatew);
    build_lists<<<1, 512, 0, stream>>>(tok_expert, tok_gatew, counts, offsets,
                                       row_token, row_gatew, pair_row);
    ffn1<<<NE * 64, 256, 0, stream>>>(x, w1, w3, counts, offsets, row_token, Hbuf);
    ffn2<<<NE * 32, 256, 0, stream>>>(Hbuf, w2, counts, offsets, row_gatew, OP);
    combine<<<1024, 256, 0, stream>>>(OP, pair_row, out);
}

// Round 2
// 512.997 us; speedup vs baseline: 1.3131x; 1.3131x over previous
//
#include <hip/hip_runtime.h>
#include <hip/hip_bf16.h>
#include <cstdint>
#include <cstddef>

// Problem constants
#define NB   64
#define NS   8
#define DIM  2048
#define FF   4096
#define NE   8
#define TOK  512            // NB*NS
#define NPAIR 1024          // TOK*2

// GEMM tiling
#define BK   64             // K-rows staged per LDS buffer
#define BN   32             // N-cols per block
#define CAP  192            // M-rows capacity per pass (Binomial(512,1/4) max ~160)

typedef __attribute__((ext_vector_type(4))) float f32x4;
typedef __attribute__((ext_vector_type(8))) short bf16x8;

#define MFMA16(a, b, c) __builtin_amdgcn_mfma_f32_16x16x32_bf16((a), (b), (c), 0, 0, 0)

// round-half-up fp32 -> bf16 (0.5 ulp max error, 2 VALU ops)
static __device__ __forceinline__ short f2bf(float f) {
    unsigned u = __builtin_bit_cast(unsigned, f);
    return (short)((u + 0x8000u) >> 16);
}

// async global->LDS DMA, 16 bytes per lane (dest must be wave-linear: base + lane*16)
static __device__ __forceinline__ void async16(float* l, const float* g) {
    __builtin_amdgcn_global_load_lds(
        (const __attribute__((address_space(1))) void*)g,
        (__attribute__((address_space(3))) void*)l, 16, 0, 0);
}

// ---------------------------------------------------------------------------
// Kernel 1: gating — per-token logits (x . gate_w), top-2, softmax over k.
// ---------------------------------------------------------------------------
__global__ void gate_topk(const float* __restrict__ x, const float* __restrict__ gw,
                          int* __restrict__ tok_expert, float* __restrict__ tok_gatew) {
    int token = blockIdx.x;
    int lane  = threadIdx.x;
    const float* xr = x + (size_t)token * DIM;

    float acc[NE];
#pragma unroll
    for (int e = 0; e < NE; ++e) acc[e] = 0.f;

    for (int d0 = lane * 8; d0 < DIM; d0 += 64 * 8) {
        float4 xa = *(const float4*)(xr + d0);
        float4 xb = *(const float4*)(xr + d0 + 4);
#pragma unroll
        for (int j = 0; j < 8; ++j) {
            float xv = (j < 4) ? ((const float*)&xa)[j] : ((const float*)&xb)[j - 4];
            const float4* g = (const float4*)(gw + (size_t)(d0 + j) * NE);
            float4 g0 = g[0], g1 = g[1];
            acc[0] += xv * g0.x; acc[1] += xv * g0.y;
            acc[2] += xv * g0.z; acc[3] += xv * g0.w;
            acc[4] += xv * g1.x; acc[5] += xv * g1.y;
            acc[6] += xv * g1.z; acc[7] += xv * g1.w;
        }
    }
#pragma unroll
    for (int off = 32; off >= 1; off >>= 1) {
#pragma unroll
        for (int e = 0; e < NE; ++e) acc[e] += __shfl_down(acc[e], off);
    }
    if (lane == 0) {
        float b1 = -1e30f, b2 = -1e30f; int i1 = 0, i2 = 0;
#pragma unroll
        for (int e = 0; e < NE; ++e) {
            float v = acc[e];
            if (v > b1) { b2 = b1; i2 = i1; b1 = v; i1 = e; }
            else if (v > b2) { b2 = v; i2 = e; }
        }
        float t = __expf(b2 - b1);
        tok_expert[token * 2 + 0] = i1;
        tok_expert[token * 2 + 1] = i2;
        tok_gatew[token * 2 + 0] = 1.f / (1.f + t);
        tok_gatew[token * 2 + 1] = t / (1.f + t);
    }
}

// ---------------------------------------------------------------------------
// Kernel 2: deterministic per-expert token lists (wave-per-expert ballot scan)
// ---------------------------------------------------------------------------
__global__ void build_lists(const int* __restrict__ tok_expert,
                            const float* __restrict__ tok_gatew,
                            int* __restrict__ counts, int* __restrict__ offsets,
                            int* __restrict__ row_token, float* __restrict__ row_gatew,
                            int* __restrict__ pair_row) {
    __shared__ int s_off[NE];
    __shared__ int s_cnt[NE];
    int e    = threadIdx.x >> 6;
    int lane = threadIdx.x & 63;
    unsigned long long lt = (1ull << lane) - 1ull;

    int cnt = 0;
    for (int base = 0; base < NPAIR; base += 64) {
        int id = tok_expert[base + lane];
        unsigned long long m = __ballot(id == e);
        cnt += __popcll(m);
    }
    if (lane == 0) s_cnt[e] = cnt;
    __syncthreads();
    if (threadIdx.x == 0) {
        int o = 0;
        for (int i = 0; i < NE; ++i) {
            int c = s_cnt[i];
            counts[i] = c; offsets[i] = o; s_off[i] = o; o += c;
        }
    }
    __syncthreads();

    int rbase = s_off[e];
    for (int base = 0; base < NPAIR; base += 64) {
        int entry = base + lane;
        int id = tok_expert[entry];
        bool match = (id == e);
        unsigned long long m = __ballot(match);
        int pre = __popcll(m & lt);
        if (match) {
            int row = rbase + pre;
            row_token[row] = entry >> 1;
            row_gatew[row] = tok_gatew[entry];
            pair_row[entry] = row;
        }
        rbase += __popcll(m);
    }
}

// ---------------------------------------------------------------------------
// Kernel 3: H = silu(X*w1) .* (X*w3) per expert group.
// grid = 1024 blocks (expert x 128 f-tiles of 32), 256 thr = 4 waves (2m x 2n).
// Weight tiles staged fp32 via global_load_lds into XOR-swizzled LDS,
// double-buffered, one __syncthreads per BK=64 stage.
// ---------------------------------------------------------------------------
__global__ __launch_bounds__(256, 3) void ffn1(
    const float* __restrict__ x, const float* __restrict__ w1,
    const float* __restrict__ w3,
    const int* __restrict__ counts, const int* __restrict__ offsets,
    const int* __restrict__ row_token, unsigned short* __restrict__ Hbuf) {
    __shared__ __align__(16) float lds1[2][BK][BN];
    __shared__ __align__(16) float lds3[2][BK][BN];

    // XCD swizzle: expert e -> XCD pair {2(e/2), 2(e/2)+1}; balances load, keeps
    // the expert's x-rows L2-resident per XCD.
    int bid = blockIdx.x;
    int xcd = bid & 7, idx = bid >> 3;          // idx 0..127
    int pr = xcd >> 1, sb = xcd & 1;
    int e    = 2 * pr + (idx & 1);
    int tile = (idx >> 1) + sb * 64;            // 0..127
    int f0 = tile * BN;

    int Me = counts[e];
    if (Me == 0) return;
    int off = offsets[e];

    int t    = threadIdx.x;
    int w    = t >> 6, lane = t & 63;
    int wm = w >> 1, wn = w & 1;
    int l15 = lane & 15, lg = lane >> 4;

    const float* w1e = w1 + (size_t)e * DIM * FF + f0;
    const float* w3e = w3 + (size_t)e * DIM * FF + f0;

    for (int sup = 0; sup * CAP < Me; ++sup) {
        const float* xp[6];
#pragma unroll
        for (int f = 0; f < 6; ++f) {
            int rl = sup * CAP + wm * 96 + f * 16 + l15;
            int tok = (rl < Me) ? row_token[off + rl] : 0;
            xp[f] = x + (size_t)tok * DIM;
        }

        f32x4 acc1[6], acc3[6];
#pragma unroll
        for (int f = 0; f < 6; ++f) {
            acc1[f] = (f32x4){0.f, 0.f, 0.f, 0.f};
            acc3[f] = (f32x4){0.f, 0.f, 0.f, 0.f};
        }

        // stage BK x BN fp32 tiles of w1,w3 into LDS buffer `buf`.
        // LDS[k][p] holds B[k][p ^ r(k)], r(k) = ((k>>3)&1)<<4  (bank de-conflict)
        auto stage = [&](int buf, int k0) {
#pragma unroll
            for (int it = 0; it < 2; ++it) {
                int fi = (it * 256 + t) * 4;            // float index in tile
                int k = fi >> 5, pp = fi & 31;
                int col = pp ^ (((k >> 3) & 1) << 4);
                size_t go = (size_t)(k0 + k) * FF + col;
                async16(&lds1[buf][k][pp], w1e + go);
                async16(&lds3[buf][k][pp], w3e + go);
            }
        };

        stage(0, 0);
        __syncthreads();                                 // drains vmcnt before barrier
        for (int s = 0; s < DIM / BK; ++s) {
            int cur = s & 1;
            if (s + 1 < DIM / BK) stage(cur ^ 1, (s + 1) * BK);   // prefetch overlaps compute
#pragma unroll
            for (int ktl = 0; ktl < 2; ++ktl) {
                int kb = s * BK + ktl * 32 + lg * 8;
                bf16x8 a_[6];
#pragma unroll
                for (int f = 0; f < 6; ++f) {
                    float4 u = *(const float4*)(xp[f] + kb);
                    float4 v = *(const float4*)(xp[f] + kb + 4);
                    a_[f][0] = f2bf(u.x); a_[f][1] = f2bf(u.y);
                    a_[f][2] = f2bf(u.z); a_[f][3] = f2bf(u.w);
                    a_[f][4] = f2bf(v.x); a_[f][5] = f2bf(v.y);
                    a_[f][6] = f2bf(v.z); a_[f][7] = f2bf(v.w);
                }
                bf16x8 b1f, b3f;
#pragma unroll
                for (int j = 0; j < 8; ++j) {
                    int k = ktl * 32 + lg * 8 + j;
                    int pp = (wn * 16 + l15) ^ (((k >> 3) & 1) << 4);
                    b1f[j] = f2bf(lds1[cur][k][pp]);
                    b3f[j] = f2bf(lds3[cur][k][pp]);
                }
#pragma unroll
                for (int f = 0; f < 6; ++f) {
                    acc1[f] = MFMA16(a_[f], b1f, acc1[f]);
                    acc3[f] = MFMA16(a_[f], b3f, acc3[f]);
                }
            }
            __syncthreads();
        }

        // epilogue: silu(a1)*a3 -> bf16 H
#pragma unroll
        for (int f = 0; f < 6; ++f)
#pragma unroll
            for (int r = 0; r < 4; ++r) {
                int rl = sup * CAP + wm * 96 + f * 16 + lg * 4 + r;
                if (rl < Me) {
                    float a1 = acc1[f][r], a3 = acc3[f][r];
                    float h = (a1 / (1.f + __expf(-a1))) * a3;
                    Hbuf[(size_t)(off + rl) * FF + f0 + wn * 16 + l15] =
                        (unsigned short)f2bf(h);
                }
            }
    }
}

// ---------------------------------------------------------------------------
// Kernel 4: OutPair = (H @ w2) * gate_weight.  Same structure, K over F.
// grid = 512 blocks (expert x 64 d-tiles of 32).
// ---------------------------------------------------------------------------
__global__ __launch_bounds__(256, 4) void ffn2(
    const unsigned short* __restrict__ Hbuf, const float* __restrict__ w2,
    const int* __restrict__ counts, const int* __restrict__ offsets,
    const float* __restrict__ row_gatew, float* __restrict__ OP) {
    __shared__ __align__(16) float ldsw[2][BK][BN];

    int bid = blockIdx.x;
    int xcd = bid & 7, idx = bid >> 3;          // idx 0..63
    int pr = xcd >> 1, sb = xcd & 1;
    int e    = 2 * pr + (idx & 1);
    int tile = (idx >> 1) + sb * 32;            // 0..63
    int d0 = tile * BN;

    int Me = counts[e];
    if (Me == 0) return;
    int off = offsets[e];

    int t    = threadIdx.x;
    int w    = t >> 6, lane = t & 63;
    int wm = w >> 1, wn = w & 1;
    int l15 = lane & 15, lg = lane >> 4;

    const float* w2e = w2 + (size_t)e * FF * DIM + d0;

    for (int sup = 0; sup * CAP < Me; ++sup) {
        const unsigned short* hp[6];
#pragma unroll
        for (int f = 0; f < 6; ++f) {
            int rl = sup * CAP + wm * 96 + f * 16 + l15;
            int ga = (rl < Me) ? (off + rl) : off;
            hp[f] = Hbuf + (size_t)ga * FF;
        }

        f32x4 acc[6];
#pragma unroll
        for (int f = 0; f < 6; ++f) acc[f] = (f32x4){0.f, 0.f, 0.f, 0.f};

        auto stage = [&](int buf, int k0) {
#pragma unroll
            for (int it = 0; it < 2; ++it) {
                int fi = (it * 256 + t) * 4;
                int k = fi >> 5, pp = fi & 31;
                int col = pp ^ (((k >> 3) & 1) << 4);
                async16(&ldsw[buf][k][pp], w2e + (size_t)(k0 + k) * DIM + col);
            }
        };

        stage(0, 0);
        __syncthreads();
        for (int s = 0; s < FF / BK; ++s) {
            int cur = s & 1;
            if (s + 1 < FF / BK) stage(cur ^ 1, (s + 1) * BK);
#pragma unroll
            for (int ktl = 0; ktl < 2; ++ktl) {
                int kb = s * BK + ktl * 32 + lg * 8;
                bf16x8 a_[6];
#pragma unroll
                for (int f = 0; f < 6; ++f)
                    a_[f] = *(const bf16x8*)(hp[f] + kb);    // already bf16, 16B
                bf16x8 bf_;
#pragma unroll
                for (int j = 0; j < 8; ++j) {
                    int k = ktl * 32 + lg * 8 + j;
                    int pp = (wn * 16 + l15) ^ (((k >> 3) & 1) << 4);
                    bf_[j] = f2bf(ldsw[cur][k][pp]);
                }
#pragma unroll
                for (int f = 0; f < 6; ++f)
                    acc[f] = MFMA16(a_[f], bf_, acc[f]);
            }
            __syncthreads();
        }

#pragma unroll
        for (int f = 0; f < 6; ++f)
#pragma unroll
            for (int r = 0; r < 4; ++r) {
                int rl = sup * CAP + wm * 96 + f * 16 + lg * 4 + r;
                if (rl < Me) {
                    int grow = off + rl;
                    float g = row_gatew[grow];
                    OP[(size_t)grow * DIM + d0 + wn * 16 + l15] = acc[f][r] * g;
                }
            }
    }
}

// ---------------------------------------------------------------------------
// Kernel 5: out[token] = OP[pair0] + OP[pair1]
// ---------------------------------------------------------------------------
__global__ void combine(const float* __restrict__ OP, const int* __restrict__ pair_row,
                        float* __restrict__ out) {
    int idx = blockIdx.x * blockDim.x + threadIdx.x;
    int token = idx >> 9;
    int q = idx & 511;
    int r0 = pair_row[token * 2 + 0];
    int r1 = pair_row[token * 2 + 1];
    float4 a = *(const float4*)(OP + (size_t)r0 * DIM + q * 4);
    float4 b = *(const float4*)(OP + (size_t)r1 * DIM + q * 4);
    float4 o;
    o.x = a.x + b.x; o.y = a.y + b.y; o.z = a.z + b.z; o.w = a.w + b.w;
    *(float4*)(out + (size_t)token * DIM + q * 4) = o;
}

// ---------------------------------------------------------------------------
extern "C" void kernel_launch(void* const* d_in, const int* in_sizes, int n_in,
                              void* d_out, int out_size, void* d_ws, size_t ws_size,
                              hipStream_t stream) {
    const float* x  = (const float*)d_in[0];
    const float* gw = (const float*)d_in[1];
    const float* w1 = (const float*)d_in[2];
    const float* w3 = (const float*)d_in[3];
    const float* w2 = (const float*)d_in[4];
    float* out = (float*)d_out;

    char* ws = (char*)d_ws;
    unsigned short* Hbuf = (unsigned short*)ws;                   // 8 MB bf16 [1024][4096]
    float* OP            = (float*)(ws + 8388608);                // 8 MB f32  [1024][2048]
    char* meta           = ws + 16777216;
    int*   tok_expert = (int*)(meta);
    float* tok_gatew  = (float*)(meta + 4096);
    int*   counts     = (int*)(meta + 8192);
    int*   offsets    = (int*)(meta + 8224);
    int*   row_token  = (int*)(meta + 8256);
    float* row_gatew  = (float*)(meta + 12352);
    int*   pair_row   = (int*)(meta + 16448);

    gate_topk<<<TOK, 64, 0, stream>>>(x, gw, tok_expert, tok_gatew);
    build_lists<<<1, 512, 0, stream>>>(tok_expert, tok_gatew, counts, offsets,
                                       row_token, row_gatew, pair_row);
    ffn1<<<NE * 128, 256, 0, stream>>>(x, w1, w3, counts, offsets, row_token, Hbuf);
    ffn2<<<NE * 64, 256, 0, stream>>>(Hbuf, w2, counts, offsets, row_gatew, OP);
    combine<<<1024, 256, 0, stream>>>(OP, pair_row, out);
}

// Round 3
// 249.060 us; speedup vs baseline: 2.7047x; 2.0597x over previous
//
#include <hip/hip_runtime.h>
#include <hip/hip_bf16.h>
#include <cstdint>
#include <cstddef>

// Problem constants
#define NB   64
#define NS   8
#define DIM  2048
#define FF   4096
#define NE   8
#define TOK  512            // NB*NS
#define NPAIR 1024          // TOK*2

// GEMM tiling
#define BM   192            // M capacity per pass (Binomial(512,1/4): mean 128, +6.5 sigma)
#define BN   64             // N-cols per block
#define BK   32             // K per stage (one 16x16x32 MFMA K-slice)

typedef __attribute__((ext_vector_type(4))) float f32x4;
typedef __attribute__((ext_vector_type(8))) short bf16x8;

#define MFMA16(a, b, c) __builtin_amdgcn_mfma_f32_16x16x32_bf16((a), (b), (c), 0, 0, 0)

// round-half-up fp32 -> bf16 (0.5 ulp, 2 VALU ops)
static __device__ __forceinline__ short f2bf(float f) {
    unsigned u = __builtin_bit_cast(unsigned, f);
    return (short)((u + 0x8000u) >> 16);
}

// async global->LDS DMA, 16 bytes/lane; LDS dest must be linear (base + lane*16),
// global source may be per-lane arbitrary (swizzle the SOURCE, never the dest).
static __device__ __forceinline__ void async16(void* l, const void* g) {
    __builtin_amdgcn_global_load_lds(
        (const __attribute__((address_space(1))) void*)g,
        (__attribute__((address_space(3))) void*)l, 16, 0, 0);
}

// ---------------------------------------------------------------------------
// Kernel 1: gating (logits -> top-2 -> softmax) + x -> bf16 preconvert.
// One wave per token.
// ---------------------------------------------------------------------------
__global__ void gate_topk(const float* __restrict__ x, const float* __restrict__ gw,
                          unsigned short* __restrict__ xbf,
                          int* __restrict__ tok_expert, float* __restrict__ tok_gatew) {
    int token = blockIdx.x;
    int lane  = threadIdx.x;
    const float* xr = x + (size_t)token * DIM;

    float acc[NE];
#pragma unroll
    for (int e = 0; e < NE; ++e) acc[e] = 0.f;

    for (int d0 = lane * 8; d0 < DIM; d0 += 64 * 8) {
        float4 xa = *(const float4*)(xr + d0);
        float4 xb = *(const float4*)(xr + d0 + 4);
        // bf16 preconvert store (16B/lane, coalesced)
        bf16x8 v;
        v[0] = f2bf(xa.x); v[1] = f2bf(xa.y); v[2] = f2bf(xa.z); v[3] = f2bf(xa.w);
        v[4] = f2bf(xb.x); v[5] = f2bf(xb.y); v[6] = f2bf(xb.z); v[7] = f2bf(xb.w);
        *(bf16x8*)(xbf + (size_t)token * DIM + d0) = v;
#pragma unroll
        for (int j = 0; j < 8; ++j) {
            float xv = (j < 4) ? ((const float*)&xa)[j] : ((const float*)&xb)[j - 4];
            const float4* g = (const float4*)(gw + (size_t)(d0 + j) * NE);
            float4 g0 = g[0], g1 = g[1];
            acc[0] += xv * g0.x; acc[1] += xv * g0.y;
            acc[2] += xv * g0.z; acc[3] += xv * g0.w;
            acc[4] += xv * g1.x; acc[5] += xv * g1.y;
            acc[6] += xv * g1.z; acc[7] += xv * g1.w;
        }
    }
#pragma unroll
    for (int off = 32; off >= 1; off >>= 1) {
#pragma unroll
        for (int e = 0; e < NE; ++e) acc[e] += __shfl_down(acc[e], off);
    }
    if (lane == 0) {
        float b1 = -1e30f, b2 = -1e30f; int i1 = 0, i2 = 0;
#pragma unroll
        for (int e = 0; e < NE; ++e) {
            float v = acc[e];
            if (v > b1) { b2 = b1; i2 = i1; b1 = v; i1 = e; }
            else if (v > b2) { b2 = v; i2 = e; }
        }
        float t = __expf(b2 - b1);
        tok_expert[token * 2 + 0] = i1;
        tok_expert[token * 2 + 1] = i2;
        tok_gatew[token * 2 + 0] = 1.f / (1.f + t);
        tok_gatew[token * 2 + 1] = t / (1.f + t);
    }
}

// ---------------------------------------------------------------------------
// Kernel 2: deterministic per-expert token lists (wave-per-expert ballot scan)
// ---------------------------------------------------------------------------
__global__ void build_lists(const int* __restrict__ tok_expert,
                            const float* __restrict__ tok_gatew,
                            int* __restrict__ counts, int* __restrict__ offsets,
                            int* __restrict__ row_token, float* __restrict__ row_gatew,
                            int* __restrict__ pair_row) {
    __shared__ int s_off[NE];
    __shared__ int s_cnt[NE];
    int e    = threadIdx.x >> 6;
    int lane = threadIdx.x & 63;
    unsigned long long lt = (1ull << lane) - 1ull;

    int cnt = 0;
    for (int base = 0; base < NPAIR; base += 64) {
        int id = tok_expert[base + lane];
        unsigned long long m = __ballot(id == e);
        cnt += __popcll(m);
    }
    if (lane == 0) s_cnt[e] = cnt;
    __syncthreads();
    if (threadIdx.x == 0) {
        int o = 0;
        for (int i = 0; i < NE; ++i) {
            int c = s_cnt[i];
            counts[i] = c; offsets[i] = o; s_off[i] = o; o += c;
        }
    }
    __syncthreads();

    int rbase = s_off[e];
    for (int base = 0; base < NPAIR; base += 64) {
        int entry = base + lane;
        int id = tok_expert[entry];
        bool match = (id == e);
        unsigned long long m = __ballot(match);
        int pre = __popcll(m & lt);
        if (match) {
            int row = rbase + pre;
            row_token[row] = entry >> 1;
            row_gatew[row] = tok_gatew[entry];
            pair_row[entry] = row;
        }
        rbase += __popcll(m);
    }
}

// ---------------------------------------------------------------------------
// Kernel 3: H = silu(Xbf*w1) .* (Xbf*w3) per expert group.
// grid = 512 (expert x 8 f-tiles... 8 experts x 64 tiles of BN=64).
// 512 thr = 8 waves (4M x 2N). A (bf16) + B (fp32) staged via global_load_lds,
// double-buffered; A chunk-XOR swizzled via source, B col-XOR via source.
// ---------------------------------------------------------------------------
__global__ __launch_bounds__(512, 4) void ffn1(
    const unsigned short* __restrict__ xbf, const float* __restrict__ w1,
    const float* __restrict__ w3,
    const int* __restrict__ counts, const int* __restrict__ offsets,
    const int* __restrict__ row_token, unsigned short* __restrict__ Hbuf) {
    __shared__ __align__(16) unsigned short Ab[2][BM * BK];   // 24 KB
    __shared__ __align__(16) float B1[2][BK][BN];             // 16 KB
    __shared__ __align__(16) float B3[2][BK][BN];             // 16 KB

    int bid = blockIdx.x;
    int e  = bid >> 6;
    int f0 = (bid & 63) * BN;

    int Me = counts[e];
    if (Me == 0) return;
    int off = offsets[e];

    int t = threadIdx.x;
    int lane = t & 63;
    int w = t >> 6;
    int wm = w >> 1, wn = w & 1;                 // 4 M-waves x 2 N-waves
    int l15 = lane & 15, lg = lane >> 4;

    const float* w1e = w1 + (size_t)e * DIM * FF + f0;
    const float* w3e = w3 + (size_t)e * DIM * FF + f0;

    // B staging: thread t -> chunk (k = t>>4, cc = t&15); source col-chunk XOR'd
    int bk = t >> 4, bcc = t & 15;
    int bcol = (bcc ^ (((bk >> 3) & 1) << 2)) * 4;
    const float* b1src = w1e + (size_t)bk * FF + bcol;
    const float* b3src = w3e + (size_t)bk * FF + bcol;

    for (int sup = 0; sup * BM < Me; ++sup) {
        int mbase = sup * BM;
        // A staging sources: chunk i = it*512+t -> (m = i>>2, c = i&3);
        // LDS slot c holds source chunk c^(m&3)
        const unsigned short* asrc[2];
#pragma unroll
        for (int it = 0; it < 2; ++it) {
            int i = it * 512 + t;
            int m = i >> 2, c = i & 3;
            int rl = mbase + m;
            int rr = (rl < Me) ? rl : (Me - 1);
            int tok = row_token[off + rr];
            asrc[it] = xbf + (size_t)tok * DIM + ((c ^ (m & 3)) << 3);
        }

        f32x4 acc1[3][2], acc3[3][2];
#pragma unroll
        for (int f = 0; f < 3; ++f)
#pragma unroll
            for (int nf = 0; nf < 2; ++nf) {
                acc1[f][nf] = (f32x4){0.f, 0.f, 0.f, 0.f};
                acc3[f][nf] = (f32x4){0.f, 0.f, 0.f, 0.f};
            }

        auto stage = [&](int buf, int k0) {
            async16(&Ab[buf][(size_t)t * 8], asrc[0] + k0);
            if (t < 256) async16(&Ab[buf][(size_t)(512 + t) * 8], asrc[1] + k0);
            async16((float*)&B1[buf][0][0] + t * 4, b1src + (size_t)k0 * FF);
            async16((float*)&B3[buf][0][0] + t * 4, b3src + (size_t)k0 * FF);
        };

        stage(0, 0);
        __syncthreads();
        for (int s = 0; s < DIM / BK; ++s) {
            int cur = s & 1;
            if (s + 1 < DIM / BK) stage(cur ^ 1, (s + 1) * BK);   // prefetch

            // A fragments: one ds_read_b128 each
            bf16x8 a[3];
#pragma unroll
            for (int f = 0; f < 3; ++f) {
                int m = wm * 48 + f * 16 + l15;
                a[f] = *(const bf16x8*)&Ab[cur][(size_t)m * BK + ((lg ^ (m & 3)) << 3)];
            }
            // B fragments: 8 conflict-free scalar reads + cvt each
#pragma unroll
            for (int nf = 0; nf < 2; ++nf) {
                int col = wn * 32 + nf * 16 + l15;
                int pp = col ^ ((lg & 1) << 4);
                bf16x8 b1f, b3f;
#pragma unroll
                for (int j = 0; j < 8; ++j) {
                    b1f[j] = f2bf(B1[cur][lg * 8 + j][pp]);
                    b3f[j] = f2bf(B3[cur][lg * 8 + j][pp]);
                }
#pragma unroll
                for (int f = 0; f < 3; ++f) {
                    acc1[f][nf] = MFMA16(a[f], b1f, acc1[f][nf]);
                    acc3[f][nf] = MFMA16(a[f], b3f, acc3[f][nf]);
                }
            }
            __syncthreads();
        }

        // epilogue: silu(a1)*a3 -> bf16 H
#pragma unroll
        for (int f = 0; f < 3; ++f)
#pragma unroll
            for (int nf = 0; nf < 2; ++nf)
#pragma unroll
                for (int r = 0; r < 4; ++r) {
                    int rl = mbase + wm * 48 + f * 16 + lg * 4 + r;
                    if (rl < Me) {
                        float a1 = acc1[f][nf][r], a3 = acc3[f][nf][r];
                        float h = (a1 / (1.f + __expf(-a1))) * a3;
                        Hbuf[(size_t)(off + rl) * FF + f0 + wn * 32 + nf * 16 + l15] =
                            (unsigned short)f2bf(h);
                    }
                }
    }
}

// ---------------------------------------------------------------------------
// Kernel 4: OutPair = (H @ w2) * gate_weight.  grid = 256 (8 experts x 32 tiles).
// ---------------------------------------------------------------------------
__global__ __launch_bounds__(512, 4) void ffn2(
    const unsigned short* __restrict__ Hbuf, const float* __restrict__ w2,
    const int* __restrict__ counts, const int* __restrict__ offsets,
    const float* __restrict__ row_gatew, float* __restrict__ OP) {
    __shared__ __align__(16) unsigned short Ab[2][BM * BK];   // 24 KB
    __shared__ __align__(16) float Bw[2][BK][BN];             // 16 KB

    int bid = blockIdx.x;
    int e  = bid >> 5;
    int d0 = (bid & 31) * BN;

    int Me = counts[e];
    if (Me == 0) return;
    int off = offsets[e];

    int t = threadIdx.x;
    int lane = t & 63;
    int w = t >> 6;
    int wm = w >> 1, wn = w & 1;
    int l15 = lane & 15, lg = lane >> 4;

    const float* w2e = w2 + (size_t)e * FF * DIM + d0;

    int bk = t >> 4, bcc = t & 15;
    int bcol = (bcc ^ (((bk >> 3) & 1) << 2)) * 4;
    const float* bsrc = w2e + (size_t)bk * DIM + bcol;

    for (int sup = 0; sup * BM < Me; ++sup) {
        int mbase = sup * BM;
        const unsigned short* asrc[2];
#pragma unroll
        for (int it = 0; it < 2; ++it) {
            int i = it * 512 + t;
            int m = i >> 2, c = i & 3;
            int rl = mbase + m;
            int rr = (rl < Me) ? rl : (Me - 1);
            asrc[it] = Hbuf + (size_t)(off + rr) * FF + ((c ^ (m & 3)) << 3);
        }

        f32x4 acc[3][2];
#pragma unroll
        for (int f = 0; f < 3; ++f)
#pragma unroll
            for (int nf = 0; nf < 2; ++nf) acc[f][nf] = (f32x4){0.f, 0.f, 0.f, 0.f};

        auto stage = [&](int buf, int k0) {
            async16(&Ab[buf][(size_t)t * 8], asrc[0] + k0);
            if (t < 256) async16(&Ab[buf][(size_t)(512 + t) * 8], asrc[1] + k0);
            async16((float*)&Bw[buf][0][0] + t * 4, bsrc + (size_t)k0 * DIM);
        };

        stage(0, 0);
        __syncthreads();
        for (int s = 0; s < FF / BK; ++s) {
            int cur = s & 1;
            if (s + 1 < FF / BK) stage(cur ^ 1, (s + 1) * BK);

            bf16x8 a[3];
#pragma unroll
            for (int f = 0; f < 3; ++f) {
                int m = wm * 48 + f * 16 + l15;
                a[f] = *(const bf16x8*)&Ab[cur][(size_t)m * BK + ((lg ^ (m & 3)) << 3)];
            }
#pragma unroll
            for (int nf = 0; nf < 2; ++nf) {
                int col = wn * 32 + nf * 16 + l15;
                int pp = col ^ ((lg & 1) << 4);
                bf16x8 bf_;
#pragma unroll
                for (int j = 0; j < 8; ++j)
                    bf_[j] = f2bf(Bw[cur][lg * 8 + j][pp]);
#pragma unroll
                for (int f = 0; f < 3; ++f)
                    acc[f][nf] = MFMA16(a[f], bf_, acc[f][nf]);
            }
            __syncthreads();
        }

#pragma unroll
        for (int f = 0; f < 3; ++f)
#pragma unroll
            for (int nf = 0; nf < 2; ++nf)
#pragma unroll
                for (int r = 0; r < 4; ++r) {
                    int rl = mbase + wm * 48 + f * 16 + lg * 4 + r;
                    if (rl < Me) {
                        int grow = off + rl;
                        float g = row_gatew[grow];
                        OP[(size_t)grow * DIM + d0 + wn * 32 + nf * 16 + l15] =
                            acc[f][nf][r] * g;
                    }
                }
    }
}

// ---------------------------------------------------------------------------
// Kernel 5: out[token] = OP[pair0] + OP[pair1]
// ---------------------------------------------------------------------------
__global__ void combine(const float* __restrict__ OP, const int* __restrict__ pair_row,
                        float* __restrict__ out) {
    int idx = blockIdx.x * blockDim.x + threadIdx.x;
    int token = idx >> 9;
    int q = idx & 511;
    int r0 = pair_row[token * 2 + 0];
    int r1 = pair_row[token * 2 + 1];
    float4 a = *(const float4*)(OP + (size_t)r0 * DIM + q * 4);
    float4 b = *(const float4*)(OP + (size_t)r1 * DIM + q * 4);
    float4 o;
    o.x = a.x + b.x; o.y = a.y + b.y; o.z = a.z + b.z; o.w = a.w + b.w;
    *(float4*)(out + (size_t)token * DIM + q * 4) = o;
}

// ---------------------------------------------------------------------------
extern "C" void kernel_launch(void* const* d_in, const int* in_sizes, int n_in,
                              void* d_out, int out_size, void* d_ws, size_t ws_size,
                              hipStream_t stream) {
    const float* x  = (const float*)d_in[0];
    const float* gw = (const float*)d_in[1];
    const float* w1 = (const float*)d_in[2];
    const float* w3 = (const float*)d_in[3];
    const float* w2 = (const float*)d_in[4];
    float* out = (float*)d_out;

    char* ws = (char*)d_ws;
    unsigned short* Hbuf = (unsigned short*)ws;                 // 8 MB bf16 [1024][4096]
    float* OP            = (float*)(ws + 8388608);              // 8 MB f32  [1024][2048]
    unsigned short* xbf  = (unsigned short*)(ws + 16777216);    // 2 MB bf16 [512][2048]
    char* meta           = ws + 18874368;
    int*   tok_expert = (int*)(meta);
    float* tok_gatew  = (float*)(meta + 4096);
    int*   counts     = (int*)(meta + 8192);
    int*   offsets    = (int*)(meta + 8224);
    int*   row_token  = (int*)(meta + 8256);
    float* row_gatew  = (float*)(meta + 12352);
    int*   pair_row   = (int*)(meta + 16448);

    gate_topk<<<TOK, 64, 0, stream>>>(x, gw, xbf, tok_expert, tok_gatew);
    build_lists<<<1, 512, 0, stream>>>(tok_expert, tok_gatew, counts, offsets,
                                       row_token, row_gatew, pair_row);
    ffn1<<<NE * 64, 512, 0, stream>>>(xbf, w1, w3, counts, offsets, row_token, Hbuf);
    ffn2<<<NE * 32, 512, 0, stream>>>(Hbuf, w2, counts, offsets, row_gatew, OP);
    combine<<<1024, 256, 0, stream>>>(OP, pair_row, out);
}